// Round 12
// baseline (2782.645 us; speedup 1.0000x reference)
//
#include <hip/hip_runtime.h>
#include <math.h>
#include <stdint.h>
#include <stddef.h>

typedef unsigned short u16;
typedef unsigned int   u32;
typedef __attribute__((ext_vector_type(8))) short short8;   // bf16x8 MFMA frag
typedef __attribute__((ext_vector_type(4))) float f32x4;

#define DI __device__ __forceinline__

// ---------------- problem constants ----------------
static constexpr int Vv = 32000, Ee = 512, Hh = 1024, Zz = 256;
static constexpr int Bb = 64, Ss = 256, Tt = 64;
static constexpr int G3 = 3 * Hh;            // 3072

// ---------------- workspace layout (bytes) ----------------
static constexpr size_t OFF_WHHE  = 0;                               // bf16 [3072][1024]
static constexpr size_t SZ_WHH    = (size_t)G3 * Hh * 2;             // 6,291,456
static constexpr size_t OFF_WHHD  = OFF_WHHE + SZ_WHH;
static constexpr size_t OFF_WIHE3 = OFF_WHHD + SZ_WHH;               // bf16 Wih (3.1MB) / buf region B
static constexpr size_t SZ_WIHE3  = (size_t)G3 * (3 * Ee) * 2;       // region B span: 9,437,184
static constexpr size_t OFF_WVOC  = OFF_WIHE3 + SZ_WIHE3;
static constexpr size_t SZ_WVOC   = (size_t)Vv * Hh * 2;             // 65,536,000
static constexpr size_t OFF_XS    = OFF_WVOC + SZ_WVOC;              // bf16 x (16.8MB) / buf region A
static constexpr size_t SZ_XS     = (size_t)Ss * Bb * (3 * Ee) * 2;  // region A span: 50,331,648
static constexpr size_t OFF_GX    = OFF_XS + SZ_XS;
static constexpr size_t SZ_GX     = (size_t)Ss * Bb * G3 * 4;        // 201,326,592
static constexpr size_t OFF_H2B   = OFF_GX;                          // overlay: GX head dead before decoder
static constexpr size_t OFF_H2F   = OFF_GX + SZ_GX;                  // buf region C during encoder
static constexpr size_t SZ_H2F    = (size_t)Tt * Bb * Hh * 4;        // 16,777,216
static constexpr size_t OFF_H     = OFF_H2F + SZ_H2F;
static constexpr size_t OFF_GXD   = OFF_H + (size_t)Bb * Hh * 4;
static constexpr size_t OFF_HENC  = OFF_GXD + 12288;
static constexpr size_t OFF_ZB    = OFF_HENC + (size_t)Bb * Zz * 4;
static constexpr size_t OFF_BV    = OFF_ZB + (size_t)Bb * Zz * 4;
static constexpr size_t OFF_BI    = OFF_BV + 16384;
static constexpr size_t OFF_BAR   = OFF_BI + 16384;
// BAR: FLG[bid*16 + w] (w<4 sub-flags), 64B line per block. 4096 u32.

static constexpr size_t SZ_HAB    = (size_t)Bb * 2 * Hh * 2;         // 262,144 per step-buffer

// ---------------- small helpers ----------------
DI u16 f2bf(float f) {                       // f32 -> bf16 RNE
  u32 u = __float_as_uint(f);
  u32 r = (u + 0x7FFFu + ((u >> 16) & 1u)) >> 16;
  return (u16)r;
}
DI float bf2f(u16 h) { return __uint_as_float(((u32)h) << 16); }

DI f32x4 mfma16(short8 a, short8 b, f32x4 c) {
  return __builtin_amdgcn_mfma_f32_16x16x32_bf16(a, b, c, 0, 0, 0);
}
DI void llds16(const u16* g, u16* l) {       // async global->LDS, 16B/lane
  __builtin_amdgcn_global_load_lds(
      (const __attribute__((address_space(1))) u32*)g,
      (__attribute__((address_space(3))) u32*)l, 16, 0, 0);
}

// agent-scope ops: write-through past L2 to L3 coherence point / L2-bypassing load.
DI void ag_store_u32(u32* p, u32 v) {
  __hip_atomic_store(p, v, __ATOMIC_RELAXED, __HIP_MEMORY_SCOPE_AGENT);
}
DI u32 ag_load_u32(const u32* p) {
  return __hip_atomic_load((u32*)p, __ATOMIC_RELAXED, __HIP_MEMORY_SCOPE_AGENT);
}
DI void ag_store_f32(float* p, float v) {
  __hip_atomic_store(p, v, __ATOMIC_RELAXED, __HIP_MEMORY_SCOPE_AGENT);
}

// per-step hA buffer: regions A (XS, 192) | B (WIHE3, 36) | C (H2F, 29). Written once
// (sc stores, step st-1), read once (plain b128, step st) -> no stale L2 copies possible.
DI u16* hbuf_dev(char* rA, char* rB, char* rC, int i) {
  if (i < 192) return (u16*)(rA + (size_t)i * SZ_HAB);
  if (i < 228) return (u16*)(rB + (size_t)(i - 192) * SZ_HAB);
  return (u16*)(rC + (size_t)(i - 228) * SZ_HAB);
}

// ---------------- utility kernels ----------------
__global__ void k_zero(u32* p, int n) {
  for (int i = blockIdx.x * 256 + threadIdx.x; i < n; i += gridDim.x * 256) p[i] = 0;
}

__global__ void k_tobf(const float* __restrict__ W, u16* __restrict__ Wb, int n) {
  for (int i = blockIdx.x * 256 + threadIdx.x; i < n; i += gridDim.x * 256) Wb[i] = f2bf(W[i]);
}

// x = emb_enc[token] gathered as plain bf16 (S*B x E)
__global__ void k_xgather(const int* __restrict__ inp, const float* __restrict__ emb,
                          u16* __restrict__ xs) {
  int n = Ss * Bb * Ee;
  for (int i = blockIdx.x * 256 + threadIdx.x; i < n; i += gridDim.x * 256) {
    int m = i >> 9, k = i & (Ee - 1);
    xs[i] = f2bf(emb[(size_t)inp[m] * Ee + k]);
  }
}

// gxd[g] = emb_dec[EOS] . Wih_d[g] + bih_d[g]   (exact f32, once)
__global__ void k_gxd(const float* __restrict__ emb_dec, const float* __restrict__ Wih_d,
                      const float* __restrict__ bih_d, float* __restrict__ gxd) {
  int g = blockIdx.x * 256 + threadIdx.x;
  if (g >= G3) return;
  const float* er = emb_dec + 2 * Ee;        // EOS_ID = 2
  const float* wr = Wih_d + (size_t)g * Ee;
  float s = 0.f;
  for (int e = 0; e < Ee; e++) s += er[e] * wr[e];
  gxd[g] = s + bih_d[g];
}

// ---------------- generic GEMM: C[m][n] = sum_k A[m][k]*B[n][k] + bias[n] ----------------
__global__ __launch_bounds__(256, 2) void gemm_bt(
    const u16* __restrict__ A, const u16* __restrict__ Bw, const float* __restrict__ bias,
    float* __restrict__ C, int M, int N, int K) {
  __shared__ __align__(16) u16 As[128 * 32];
  __shared__ __align__(16) u16 Bs[128 * 32];
  int tid = threadIdx.x;
  int wave = tid >> 6, lane = tid & 63;
  int wr = wave >> 1, wc = wave & 1;
  int m0 = blockIdx.y * 128, n0 = blockIdx.x * 128;
  f32x4 acc[4][4];
#pragma unroll
  for (int i = 0; i < 4; i++)
#pragma unroll
    for (int j = 0; j < 4; j++) acc[i][j] = (f32x4){0.f, 0.f, 0.f, 0.f};

  int lrow = lane >> 2, lcol = (lane & 3) * 8;
  int r15 = lane & 15, kk = (lane >> 4) * 8;

  for (int k0 = 0; k0 < K; k0 += 32) {
    __syncthreads();
#pragma unroll
    for (int rch = 0; rch < 2; rch++) {
      int c = rch * 4 + wave;
      int row = c * 16 + lrow;
      llds16(A  + (size_t)(m0 + row) * K + k0 + lcol, &As[c * 512]);
      llds16(Bw + (size_t)(n0 + row) * K + k0 + lcol, &Bs[c * 512]);
    }
    __syncthreads();
    short8 af[4], bfv[4];
#pragma unroll
    for (int mi = 0; mi < 4; mi++)
      af[mi] = *(const short8*)&As[(wr * 64 + mi * 16 + r15) * 32 + kk];
#pragma unroll
    for (int ni = 0; ni < 4; ni++)
      bfv[ni] = *(const short8*)&Bs[(wc * 64 + ni * 16 + r15) * 32 + kk];
#pragma unroll
    for (int mi = 0; mi < 4; mi++)
#pragma unroll
      for (int ni = 0; ni < 4; ni++) acc[mi][ni] = mfma16(af[mi], bfv[ni], acc[mi][ni]);
  }
#pragma unroll
  for (int mi = 0; mi < 4; mi++)
#pragma unroll
    for (int ni = 0; ni < 4; ni++) {
      int col = n0 + wc * 64 + ni * 16 + r15;
      float bs = bias[col];
#pragma unroll
      for (int i = 0; i < 4; i++) {
        int row = m0 + wr * 64 + mi * 16 + (lane >> 4) * 4 + i;
        C[(size_t)row * N + col] = acc[mi][ni][i] + bs;
      }
    }
}

// Grouped 1D-grid variant for the vocab GEMM (B slice L2-resident per XCD).
__global__ __launch_bounds__(256, 2) void gemm_grp(
    const u16* __restrict__ A, const u16* __restrict__ Bw, const float* __restrict__ bias,
    float* __restrict__ C, int M, int N, int K, int GN) {
  __shared__ __align__(16) u16 As[128 * 32];
  __shared__ __align__(16) u16 Bs[128 * 32];
  int tid = threadIdx.x;
  int wave = tid >> 6, lane = tid & 63;
  int wr = wave >> 1, wc = wave & 1;
  int mp = M >> 7;
  int perg = mp * GN;
  int grp = blockIdx.x / perg;
  int rem = blockIdx.x - grp * perg;
  int m0 = (rem / GN) * 128;
  int n0 = (grp * GN + rem % GN) * 128;
  f32x4 acc[4][4];
#pragma unroll
  for (int i = 0; i < 4; i++)
#pragma unroll
    for (int j = 0; j < 4; j++) acc[i][j] = (f32x4){0.f, 0.f, 0.f, 0.f};

  int lrow = lane >> 2, lcol = (lane & 3) * 8;
  int r15 = lane & 15, kk = (lane >> 4) * 8;

  for (int k0 = 0; k0 < K; k0 += 32) {
    __syncthreads();
#pragma unroll
    for (int rch = 0; rch < 2; rch++) {
      int c = rch * 4 + wave;
      int row = c * 16 + lrow;
      llds16(A  + (size_t)(m0 + row) * K + k0 + lcol, &As[c * 512]);
      llds16(Bw + (size_t)(n0 + row) * K + k0 + lcol, &Bs[c * 512]);
    }
    __syncthreads();
    short8 af[4], bfv[4];
#pragma unroll
    for (int mi = 0; mi < 4; mi++)
      af[mi] = *(const short8*)&As[(wr * 64 + mi * 16 + r15) * 32 + kk];
#pragma unroll
    for (int ni = 0; ni < 4; ni++)
      bfv[ni] = *(const short8*)&Bs[(wc * 64 + ni * 16 + r15) * 32 + kk];
#pragma unroll
    for (int mi = 0; mi < 4; mi++)
#pragma unroll
      for (int ni = 0; ni < 4; ni++) acc[mi][ni] = mfma16(af[mi], bfv[ni], acc[mi][ni]);
  }
#pragma unroll
  for (int mi = 0; mi < 4; mi++)
#pragma unroll
    for (int ni = 0; ni < 4; ni++) {
      int col = n0 + wc * 64 + ni * 16 + r15;
      float bs = bias[col];
#pragma unroll
      for (int i = 0; i < 4; i++) {
        int row = m0 + wr * 64 + mi * 16 + (lane >> 4) * 4 + i;
        C[(size_t)row * N + col] = acc[mi][ni][i] + bs;
      }
    }
}

// ---------------- persistent GRU phase (v7: per-wave producer-set polling) ----------------
// grid 256 = 64 jt x 4 bq; block 512 = 8 waves splitting K=1024 into 8x128.
// Wave w reads A columns [128w,128w+128) -> produced by exactly 8 blocks jt'=8w..8w+7
// (same bq). Each store-wave (0-3) publishes sub-flag FLG[bid*16+w] after its OWN vmcnt
// drain; every wave polls only its 8 producers x 4 sub-flags (one 64-lane load/iter)
// and proceeds independently. Two block-syncs per step (was four); no global coupling.
template <int DEC>
__global__ __launch_bounds__(512, 1) void k_pers(
    const u16* __restrict__ W, const float* __restrict__ bhh, const float* __restrict__ gx0,
    char* rA, char* rB, char* rC, float* Hst, float* h2f0, u16* h2b0, u32* bar) {
  int tid = threadIdx.x, wave = tid >> 6, lane = tid & 63;
  int r15 = lane & 15, kk = (lane >> 4) * 8;
  int bq = blockIdx.x & 3, jt = blockIdx.x >> 2;
  int b0 = bq * 16, j0 = jt * 16;
  int kbase = wave * 128;
  const int NSTEP = DEC ? Tt : Ss;

  __shared__ float sC[8][64][13];              // stride 13 -> conflict-free
  __shared__ float hT[256];                    // h tile [bl*16+jc]
  __shared__ __align__(8) u16 stg[2][16][16];  // hi/lo staging

  int bl = tid >> 4, jc = tid & 15;            // epilogue mapping (tid<256)
  float br = 0.f, bz = 0.f, bn = 0.f;
  float xr = 0.f, xz = 0.f, xn = 0.f;
  if (tid < 256) {
    hT[tid] = DEC ? Hst[(size_t)(b0 + bl) * Hh + j0 + jc] : 0.f;
    int j = j0 + jc;
    br = bhh[j]; bz = bhh[Hh + j]; bn = bhh[2 * Hh + j];
    if (DEC) { xr = gx0[j]; xz = gx0[Hh + j]; xn = gx0[2 * Hh + j]; }
    else {                                     // prologue gx load, step 0
      const float* gr = gx0 + (size_t)(b0 + bl) * G3;
      xr = gr[j]; xz = gr[Hh + j]; xn = gr[2 * Hh + j];
    }
  }
  __syncthreads();

  const u16* Wrow = W + (size_t)(j0 + r15) * Hh + kbase + kk;
  int lsrc = (bl >> 2) * 16 + jc;              // partials source for (bl,jc)
  int isrc = bl & 3;
  // per-wave poll address: 8 producers (jt'=8w+p, same bq) x 4 sub-flags
  int cmb = lane & 31, pp = cmb >> 2, sub = cmb & 3;
  u32* fa = &bar[(((wave * 8 + pp) << 2) | bq) * 16 + sub];

  for (int st = 0; st < NSTEP; st++) {
    const u16* hin = hbuf_dev(rA, rB, rC, st);

    f32x4 acc[3];
#pragma unroll
    for (int g = 0; g < 3; g++) acc[g] = (f32x4){0.f, 0.f, 0.f, 0.f};
    const u16* Ab = hin + (size_t)(b0 + r15) * 2048 + kbase + kk;
#pragma unroll
    for (int ks = 0; ks < 4; ks++) {
      int ko = ks * 32;
      short8 ah = *(const short8*)(Ab + ko);          // h_hi (plain b128)
      short8 al = *(const short8*)(Ab + 1024 + ko);   // h_lo
      short8 w0 = *(const short8*)(Wrow + ko);
      short8 w1 = *(const short8*)(Wrow + (size_t)Hh * Hh + ko);
      short8 w2 = *(const short8*)(Wrow + (size_t)2 * Hh * Hh + ko);
      acc[0] = mfma16(ah, w0, acc[0]);
      acc[1] = mfma16(ah, w1, acc[1]);
      acc[2] = mfma16(ah, w2, acc[2]);
      acc[0] = mfma16(al, w0, acc[0]);
      acc[1] = mfma16(al, w1, acc[1]);
      acc[2] = mfma16(al, w2, acc[2]);
    }
#pragma unroll
    for (int g = 0; g < 3; g++)
#pragma unroll
      for (int i = 0; i < 4; i++) sC[wave][lane][g * 4 + i] = acc[g][i];
    __syncthreads();                            // #1: sC ready for epilogue

    if (tid < 256) {
      float hgr = br, hgz = bz, hgn = bn;
#pragma unroll
      for (int w = 0; w < 8; w++) {              // fixed order -> deterministic
        hgr += sC[w][lsrc][isrc];
        hgz += sC[w][lsrc][4 + isrc];
        hgn += sC[w][lsrc][8 + isrc];
      }
      float rg = 1.0f / (1.0f + expf(-(xr + hgr)));
      float zg = 1.0f / (1.0f + expf(-(xz + hgz)));
      float ng = tanhf(xn + rg * hgn);
      float hn = (1.0f - zg) * ng + zg * hT[tid];
      hT[tid] = hn;
      u16 hi = f2bf(hn), lo = f2bf(hn - bf2f(hi));
      stg[0][bl][jc] = hi;
      stg[1][bl][jc] = lo;
      if (DEC) ag_store_f32(&h2f0[((size_t)st * Bb + b0 + bl) * Hh + j0 + jc], hn);
    }
    __syncthreads();                            // #2: stg ready; sC consumed

    // distributed sc stores (hbuf skipped on last step; h2b every step for DEC)
    if (tid < 256) {
      int part = tid >> 7, idx = tid & 127, row = idx >> 3, dw = idx & 7;
      if (st + 1 < NSTEP) {
        u16* hout = hbuf_dev(rA, rB, rC, st + 1);
        u32 val = ((const u32*)&stg[part][row][0])[dw];
        ag_store_u32((u32*)(hout + (size_t)(b0 + row) * 2048 + part * 1024 + j0) + dw, val);
      }
      if (DEC && tid < 128) {
        u16* h2b = h2b0 + (size_t)st * Bb * Hh;
        ag_store_u32((u32*)(h2b + (size_t)(b0 + row) * Hh + j0) + dw,
                     ((const u32*)&stg[0][row][0])[dw]);
      }
    }

    if (st + 1 < NSTEP) {
      if (wave < 4) {                           // store-waves: own drain -> own sub-flag
        asm volatile("s_waitcnt vmcnt(0)" ::: "memory");
        if (lane == 0)
          ag_store_u32(&bar[blockIdx.x * 16 + wave], (u32)(st + 1));
      }
      // prefetch gx(st+1) under the poll (encoder only; waves 0-3)
      if (!DEC && tid < 256) {
        const float* gr = gx0 + ((size_t)(st + 1) * Bb + b0 + bl) * G3;
        int j = j0 + jc;
        xr = gr[j]; xz = gr[Hh + j]; xn = gr[2 * Hh + j];
      }
      for (;;) {                                // each wave: its own 8 producers only
        int v = (int)ag_load_u32(fa);
        if (__all(v >= st + 1)) break;
        __builtin_amdgcn_s_sleep(1);
      }
      // no block sync: waves proceed independently into step st+1
    }
  }

  if (!DEC && tid < 256)
    Hst[(size_t)(b0 + bl) * Hh + j0 + jc] = hT[tid];
}

// ---------------- fallback per-step kernel (if coop launch fails) ----------------
template <int DEC>
__global__ __launch_bounds__(512, 1) void k_step3(
    const u16* __restrict__ W, const float* __restrict__ bhh, const float* __restrict__ gxp,
    const u16* __restrict__ hAin, u16* __restrict__ hAout, float* __restrict__ h,
    float* __restrict__ h2f, u16* __restrict__ h2b) {
  __shared__ float sC[4][64][13];
  int tid = threadIdx.x, wave = tid >> 6, lane = tid & 63;
  int mw = wave & 3, khalf = wave >> 2;
  int m0 = mw * 16;
  int r15 = lane & 15, kk = (lane >> 4) * 8;
  int j0 = blockIdx.x * 16;
  int kbase = khalf * 512;

  f32x4 acc[3];
#pragma unroll
  for (int g = 0; g < 3; g++) acc[g] = (f32x4){0.f, 0.f, 0.f, 0.f};

  const u16* Ah = hAin + (size_t)(m0 + r15) * 2048 + kbase + kk;
  const u16* Wr = W + (size_t)(j0 + r15) * Hh + kbase + kk;
#pragma unroll 4
  for (int ks = 0; ks < 16; ks++) {
    int ko = ks * 32;
    short8 ah = *(const short8*)(Ah + ko);
    short8 al = *(const short8*)(Ah + 1024 + ko);
    short8 b0 = *(const short8*)(Wr + ko);
    short8 b1 = *(const short8*)(Wr + (size_t)Hh * Hh + ko);
    short8 b2 = *(const short8*)(Wr + (size_t)2 * Hh * Hh + ko);
    acc[0] = mfma16(ah, b0, acc[0]);
    acc[1] = mfma16(ah, b1, acc[1]);
    acc[2] = mfma16(ah, b2, acc[2]);
    acc[0] = mfma16(al, b0, acc[0]);
    acc[1] = mfma16(al, b1, acc[1]);
    acc[2] = mfma16(al, b2, acc[2]);
  }

  if (khalf == 1) {
#pragma unroll
    for (int g = 0; g < 3; g++)
#pragma unroll
      for (int i = 0; i < 4; i++) sC[mw][lane][g * 4 + i] = acc[g][i];
  }
  __syncthreads();
  if (khalf == 1) return;

  int j = j0 + r15;
  float br = bhh[j], bz = bhh[Hh + j], bn = bhh[2 * Hh + j];
  float xrD = 0.f, xzD = 0.f, xnD = 0.f;
  if (DEC) { xrD = gxp[j]; xzD = gxp[Hh + j]; xnD = gxp[2 * Hh + j]; }
#pragma unroll
  for (int i = 0; i < 4; i++) {
    int b = m0 + (lane >> 4) * 4 + i;
    float hgr = acc[0][i] + sC[mw][lane][i]     + br;
    float hgz = acc[1][i] + sC[mw][lane][4 + i] + bz;
    float hgn = acc[2][i] + sC[mw][lane][8 + i] + bn;
    float xr, xz, xn;
    if (DEC) { xr = xrD; xz = xzD; xn = xnD; }
    else {
      const float* gr = gxp + (size_t)b * G3;
      xr = gr[j]; xz = gr[Hh + j]; xn = gr[2 * Hh + j];
    }
    float rg = 1.0f / (1.0f + expf(-(xr + hgr)));
    float zg = 1.0f / (1.0f + expf(-(xz + hgz)));
    float ng = tanhf(xn + rg * hgn);
    float hold = h[(size_t)b * Hh + j];
    float hn = (1.0f - zg) * ng + zg * hold;
    h[(size_t)b * Hh + j] = hn;
    u16 hi = f2bf(hn);
    u16 lo = f2bf(hn - bf2f(hi));
    hAout[(size_t)b * 2048 + j] = hi;
    hAout[(size_t)b * 2048 + 1024 + j] = lo;
    if (DEC) {
      h2f[(size_t)b * Hh + j] = hn;
      h2b[(size_t)b * Hh + j] = hi;
    }
  }
}

// ---------------- heads (exact f32) ----------------
__global__ __launch_bounds__(256, 2) void k_head1(const float* __restrict__ h,
    const float* __restrict__ Wenc, const float* __restrict__ benc, float* __restrict__ henc) {
  int b = blockIdx.x;
  __shared__ float hs[Hh];
  for (int k = threadIdx.x; k < Hh; k += 256) hs[k] = h[(size_t)b * Hh + k];
  __syncthreads();
  int q = threadIdx.x;
  const float* wrw = Wenc + (size_t)q * Hh;
  float s = 0.f;
  for (int k = 0; k < Hh; k++) s += hs[k] * wrw[k];
  henc[b * Zz + q] = s + benc[q];
}

__global__ __launch_bounds__(256, 2) void k_head2(const float* __restrict__ henc,
    const float* __restrict__ Wloc, const float* __restrict__ bloc,
    const float* __restrict__ Wsc, const float* __restrict__ bsc,
    const float* __restrict__ eps, float* __restrict__ outLoc, float* __restrict__ outSc,
    float* __restrict__ zb) {
  int b = blockIdx.x;
  __shared__ float hs[Zz];
  if (threadIdx.x < Zz) hs[threadIdx.x] = henc[b * Zz + threadIdx.x];
  __syncthreads();
  int q = threadIdx.x;
  const float* wl = Wloc + (size_t)q * Zz;
  const float* wsp = Wsc + (size_t)q * Zz;
  float sl = 0.f, ssum = 0.f;
  for (int k = 0; k < Zz; k++) { sl += hs[k] * wl[k]; ssum += hs[k] * wsp[k]; }
  sl += bloc[q]; ssum += bsc[q];
  float sp = fmaxf(ssum, 0.f) + log1pf(expf(-fabsf(ssum)));  // softplus, stable
  float zv = sl + eps[b * Zz + q] * expf(0.5f * sp);
  outLoc[b * Zz + q] = sl;
  outSc[b * Zz + q] = sp;
  zb[b * Zz + q] = zv;
}

__global__ __launch_bounds__(256, 2) void k_head3(const float* __restrict__ zb,
    const float* __restrict__ Wdec, const float* __restrict__ bdec,
    float* __restrict__ h, u16* __restrict__ hA0) {
  int b = blockIdx.x;
  __shared__ float zs[Zz];
  if (threadIdx.x < Zz) zs[threadIdx.x] = zb[b * Zz + threadIdx.x];
  __syncthreads();
  for (int j = threadIdx.x; j < Hh; j += 256) {
    const float* wrw = Wdec + (size_t)j * Zz;
    float s = 0.f;
    for (int k = 0; k < Zz; k++) s += zs[k] * wrw[k];
    s += bdec[j];
    h[(size_t)b * Hh + j] = s;
    u16 hi = f2bf(s);
    u16 lo = f2bf(s - bf2f(hi));
    hA0[(size_t)b * 2048 + j] = hi;
    hA0[(size_t)b * 2048 + 1024 + j] = lo;
  }
}

// ---------------- fused softmax v3: row held in registers, 1 read + 1 write ----------------
// One block (1024 thr) per row. Each thread keeps its 32 elements in 8 f32x4 regs:
// max pass, sumexp+candidates, and the subtract+write all run from registers.
// Fixed-order reductions + sorted candidates -> deterministic.
__global__ __launch_bounds__(1024, 4) void k_soft(
    float* __restrict__ logits, const float* __restrict__ h2f,
    const float* __restrict__ Wvoc, const float* __restrict__ bvoc,
    float* __restrict__ bestv, int* __restrict__ besti) {
  __shared__ float hrow[Hh];
  __shared__ float red[16];
  __shared__ float srm, ssum, slse;
  __shared__ int lcnt, scc;
  __shared__ int lcand[32];
  __shared__ float lex[32], del[32];
  int r = blockIdx.x;
  int tid = threadIdx.x, wave = tid >> 6, lane = tid & 63;
  float* grow = logits + (size_t)r * Vv;
  if (tid == 0) lcnt = 0;
  hrow[tid] = h2f[(size_t)r * Hh + tid];
  f32x4 vals[8];
  float m = -3.0e38f;
#pragma unroll
  for (int it = 0; it < 8; it++) {
    int c = tid * 4 + it * 4096;
    if (c < Vv) {
      vals[it] = *(const f32x4*)(grow + c);
      m = fmaxf(fmaxf(m, vals[it].x), fmaxf(vals[it].y, fmaxf(vals[it].z, vals[it].w)));
    }
  }
  for (int o = 32; o; o >>= 1) m = fmaxf(m, __shfl_xor(m, o));
  if (lane == 0) red[wave] = m;
  __syncthreads();
  if (tid == 0) {
    float t = red[0];
    for (int i = 1; i < 16; i++) t = fmaxf(t, red[i]);
    srm = t;
  }
  __syncthreads();
  float rm = srm;
  float s = 0.f;
#pragma unroll
  for (int it = 0; it < 8; it++) {
    int c = tid * 4 + it * 4096;
    if (c < Vv) {
      f32x4 v = vals[it];
      s += expf(v.x - rm) + expf(v.y - rm) + expf(v.z - rm) + expf(v.w - rm);
      if (v.x >= rm - 0.0625f) { int sl = atomicAdd(&lcnt, 1); if (sl < 32) lcand[sl] = c; }
      if (v.y >= rm - 0.0625f) { int sl = atomicAdd(&lcnt, 1); if (sl < 32) lcand[sl] = c + 1; }
      if (v.z >= rm - 0.0625f) { int sl = atomicAdd(&lcnt, 1); if (sl < 32) lcand[sl] = c + 2; }
      if (v.w >= rm - 0.0625f) { int sl = atomicAdd(&lcnt, 1); if (sl < 32) lcand[sl] = c + 3; }
    }
  }
  for (int o = 32; o; o >>= 1) s += __shfl_xor(s, o);
  if (lane == 0) red[wave] = s;
  __syncthreads();
  if (tid == 0) {
    float t = 0.f;
    for (int i = 0; i < 16; i++) t += red[i];       // fixed order -> deterministic
    ssum = t;
    int cc = lcnt < 32 ? lcnt : 32;
    for (int i = 0; i < cc; i++)                    // sort ascending -> determinism
      for (int k2 = i + 1; k2 < cc; k2++)
        if (lcand[k2] < lcand[i]) { int q = lcand[i]; lcand[i] = lcand[k2]; lcand[k2] = q; }
    scc = cc;
  }
  __syncthreads();
  int cnt = scc;
  for (int ci = wave; ci < cnt; ci += 16) {         // exact-f32 candidate recompute
    int v = lcand[ci];
    const float* wrw = Wvoc + (size_t)v * Hh;
    float sd = 0.f;
    for (int k = lane; k < Hh; k += 64) sd += hrow[k] * wrw[k];
    for (int o = 32; o; o >>= 1) sd += __shfl_xor(sd, o);
    if (lane == 0) {
      float le = sd + bvoc[v];
      lex[ci] = le;
      del[ci] = expf(le - rm) - expf(grow[v] - rm);
    }
  }
  __syncthreads();
  if (tid == 0) {
    float se = ssum;
    for (int i = 0; i < cnt; i++) se += del[i];
    float lse = rm + logf(se);
    slse = lse;
    float bv = -3.0e38f; int bvi = 0;
    for (int i = 0; i < cnt; i++)
      if (lex[i] > bv) { bv = lex[i]; bvi = lcand[i]; }  // sorted -> ties keep lowest v
    bestv[r] = bv - lse;
    besti[r] = (r & 63) * Vv + bvi;                  // flat index b*V + v
  }
  __syncthreads();
  float l = slse;
#pragma unroll
  for (int it = 0; it < 8; it++) {
    int c = tid * 4 + it * 4096;
    if (c < Vv) {
      f32x4 v = vals[it];
      v.x -= l; v.y -= l; v.z -= l; v.w -= l;
      *(f32x4*)(grow + c) = v;
    }
  }
}

// ---------------- per-step global argmax -> seq ----------------
__global__ void k_argmax(const float* __restrict__ bestv, const int* __restrict__ besti,
                         float* __restrict__ outseq) {
  int tid = threadIdx.x;
  if (tid == 0) outseq[0] = 1.0f;
  for (int t = 0; t < Tt; t++) {
    float v = bestv[t * 64 + tid];
    int ii = besti[t * 64 + tid];
    for (int o = 1; o < 64; o <<= 1) {
      float ov = __shfl_xor(v, o);
      int oi = __shfl_xor(ii, o);
      if (ov > v || (ov == v && oi < ii)) { v = ov; ii = oi; }
    }
    if (tid == 0) outseq[1 + t] = (float)ii;
  }
}

// ---------------- host: launch sequence ----------------
extern "C" void kernel_launch(void* const* d_in, const int* in_sizes, int n_in,
                              void* d_out, int out_size, void* d_ws, size_t ws_size,
                              hipStream_t stream) {
  (void)in_sizes; (void)n_in; (void)out_size; (void)ws_size;
  const int*   inp     = (const int*)d_in[0];
  const float* eps     = (const float*)d_in[1];
  const float* emb_enc = (const float*)d_in[2];
  const float* Wih_e   = (const float*)d_in[3];
  const float* Whh_e   = (const float*)d_in[4];
  const float* bih_e   = (const float*)d_in[5];
  const float* bhh_e   = (const float*)d_in[6];
  const float* W_enc   = (const float*)d_in[7];
  const float* b_enc   = (const float*)d_in[8];
  const float* W_loc   = (const float*)d_in[9];
  const float* b_loc   = (const float*)d_in[10];
  const float* W_sc    = (const float*)d_in[11];
  const float* b_sc    = (const float*)d_in[12];
  const float* emb_dec = (const float*)d_in[13];
  const float* W_dec   = (const float*)d_in[14];
  const float* b_dec   = (const float*)d_in[15];
  const float* Wih_d   = (const float*)d_in[16];
  const float* Whh_d   = (const float*)d_in[17];
  const float* bih_d   = (const float*)d_in[18];
  const float* bhh_d   = (const float*)d_in[19];
  const float* W_voc   = (const float*)d_in[20];
  const float* b_voc   = (const float*)d_in[21];

  char* ws = (char*)d_ws;
  u16*   WHHE  = (u16*)(ws + OFF_WHHE);
  u16*   WHHD  = (u16*)(ws + OFF_WHHD);
  u16*   WIHB  = (u16*)(ws + OFF_WIHE3);      // plain bf16 Wih_e [3072][512]
  u16*   WVOC  = (u16*)(ws + OFF_WVOC);
  u16*   XS    = (u16*)(ws + OFF_XS);         // plain bf16 x [16384][512]
  float* GX    = (float*)(ws + OFF_GX);
  float* Hst   = (float*)(ws + OFF_H);
  float* H2F   = (float*)(ws + OFF_H2F);
  u16*   H2B   = (u16*)(ws + OFF_H2B);
  float* GXD   = (float*)(ws + OFF_GXD);
  float* HENC  = (float*)(ws + OFF_HENC);
  float* ZB    = (float*)(ws + OFF_ZB);
  float* BV    = (float*)(ws + OFF_BV);
  int*   BI    = (int*)(ws + OFF_BI);
  u32*   BAR   = (u32*)(ws + OFF_BAR);

  char* rA = ws + OFF_XS;      // step-buffer regions
  char* rB = ws + OFF_WIHE3;
  char* rC = ws + OFF_H2F;
  auto hbuf = [&](int i) -> u16* {
    if (i < 192) return (u16*)(rA + (size_t)i * SZ_HAB);
    if (i < 228) return (u16*)(rB + (size_t)(i - 192) * SZ_HAB);
    return (u16*)(rC + (size_t)(i - 228) * SZ_HAB);
  };

  float* out     = (float*)d_out;
  float* logits  = out;                                   // (T*B, V) f32
  float* outseq  = out + (size_t)Tt * Bb * Vv;
  float* outloc  = outseq + (Tt + 1);
  float* outsc   = outloc + Bb * Zz;

  // --- weight conversions ---
  k_tobf<<<1024, 256, 0, stream>>>(Whh_e, WHHE, G3 * Hh);
  k_tobf<<<1024, 256, 0, stream>>>(Whh_d, WHHD, G3 * Hh);
  k_tobf<<<512, 256, 0, stream>>>(Wih_e, WIHB, G3 * Ee);
  k_tobf<<<2048, 256, 0, stream>>>(W_voc, WVOC, Vv * Hh);
  k_xgather<<<2048, 256, 0, stream>>>(inp, emb_enc, XS);

  // --- gx = x * Wih_e^T + bih_e   (M=16384, N=3072, K=512, plain bf16) ---
  {
    dim3 g(G3 / 128, (Ss * Bb) / 128);
    gemm_bt<<<g, 256, 0, stream>>>(XS, WIHB, bih_e, GX, Ss * Bb, G3, Ee);
  }
  k_gxd<<<12, 256, 0, stream>>>(emb_dec, Wih_d, bih_d, GXD);
  k_zero<<<64, 256, 0, stream>>>((u32*)hbuf(0), (int)(SZ_HAB / 4));  // h0 = 0
  k_zero<<<1, 256, 0, stream>>>(BAR, 4096);

  // --- encoder: persistent cooperative (256 steps), fallback = per-step loop ---
  hipError_t ce;
  {
    const u16* a0 = WHHE; const float* a1 = bhh_e; const float* a2 = GX;
    char* a3 = rA; char* a4 = rB; char* a5 = rC; float* a6 = Hst;
    float* a7 = nullptr; u16* a8 = nullptr; u32* a9 = BAR;
    void* args[] = {&a0,&a1,&a2,&a3,&a4,&a5,&a6,&a7,&a8,&a9};
    ce = hipLaunchCooperativeKernel(reinterpret_cast<void*>(&k_pers<0>),
                                    dim3(256), dim3(512), args, 0, stream);
  }
  if (ce != hipSuccess) {
    for (int s = 0; s < Ss; s++)
      k_step3<0><<<64, 512, 0, stream>>>(WHHE, bhh_e, GX + (size_t)s * Bb * G3,
                                         hbuf(s), hbuf(s + 1), Hst, nullptr, nullptr);
  }

  // --- heads ---
  k_head1<<<64, 256, 0, stream>>>(Hst, W_enc, b_enc, HENC);
  k_head2<<<64, 256, 0, stream>>>(HENC, W_loc, b_loc, W_sc, b_sc, eps, outloc, outsc, ZB);
  k_head3<<<64, 256, 0, stream>>>(ZB, W_dec, b_dec, Hst, hbuf(0));
  k_zero<<<1, 256, 0, stream>>>(BAR, 4096);

  // --- decoder: persistent cooperative (64 steps), fallback = per-step loop ---
  {
    const u16* a0 = WHHD; const float* a1 = bhh_d; const float* a2 = GXD;
    char* a3 = rA; char* a4 = rB; char* a5 = rC; float* a6 = Hst;
    float* a7 = H2F; u16* a8 = H2B; u32* a9 = BAR;
    void* args[] = {&a0,&a1,&a2,&a3,&a4,&a5,&a6,&a7,&a8,&a9};
    hipError_t cd = hipLaunchCooperativeKernel(reinterpret_cast<void*>(&k_pers<1>),
                                               dim3(256), dim3(512), args, 0, stream);
    if (cd != hipSuccess) {
      for (int t = 0; t < Tt; t++)
        k_step3<1><<<64, 512, 0, stream>>>(WHHD, bhh_d, GXD, hbuf(t), hbuf(t + 1), Hst,
                                           H2F + (size_t)t * Bb * Hh,
                                           H2B + (size_t)t * Bb * Hh);
    }
  }

  // --- vocab projection: logits = h2 * Wvoc^T + b_voc  (M=4096, N=32000, K=1024) ---
  gemm_grp<<<8000, 256, 0, stream>>>(H2B, WVOC, b_voc, logits, Tt * Bb, Vv, Hh, 5);

  // --- fused softmax (stats + exact argmax refine + in-place log-softmax) ---
  k_soft<<<Tt * Bb, 1024, 0, stream>>>(logits, H2F, W_voc, b_voc, BV, BI);
  k_argmax<<<1, 64, 0, stream>>>(BV, BI, outseq);
}

// Round 13
// 2575.112 us; speedup vs baseline: 1.0806x; 1.0806x over previous
//
#include <hip/hip_runtime.h>
#include <math.h>
#include <stdint.h>
#include <stddef.h>

typedef unsigned short u16;
typedef unsigned int   u32;
typedef __attribute__((ext_vector_type(8))) short short8;   // bf16x8 MFMA frag
typedef __attribute__((ext_vector_type(4))) float f32x4;

#define DI __device__ __forceinline__

// ---------------- problem constants ----------------
static constexpr int Vv = 32000, Ee = 512, Hh = 1024, Zz = 256;
static constexpr int Bb = 64, Ss = 256, Tt = 64;
static constexpr int G3 = 3 * Hh;            // 3072

// ---------------- workspace layout (bytes) ----------------
static constexpr size_t OFF_WHHE  = 0;                               // bf16 [3072][1024]
static constexpr size_t SZ_WHH    = (size_t)G3 * Hh * 2;             // 6,291,456
static constexpr size_t OFF_WHHD  = OFF_WHHE + SZ_WHH;
static constexpr size_t OFF_WIHE3 = OFF_WHHD + SZ_WHH;               // bf16 Wih (3.1MB) / buf region B
static constexpr size_t SZ_WIHE3  = (size_t)G3 * (3 * Ee) * 2;       // region B span: 9,437,184
static constexpr size_t OFF_WVOC  = OFF_WIHE3 + SZ_WIHE3;
static constexpr size_t SZ_WVOC   = (size_t)Vv * Hh * 2;             // 65,536,000
static constexpr size_t OFF_XS    = OFF_WVOC + SZ_WVOC;              // bf16 x (16.8MB) / buf region A
static constexpr size_t SZ_XS     = (size_t)Ss * Bb * (3 * Ee) * 2;  // region A span: 50,331,648
static constexpr size_t OFF_GX    = OFF_XS + SZ_XS;
static constexpr size_t SZ_GX     = (size_t)Ss * Bb * G3 * 4;        // 201,326,592
static constexpr size_t OFF_H2B   = OFF_GX;                          // overlay: GX head dead before decoder
static constexpr size_t OFF_H2F   = OFF_GX + SZ_GX;                  // buf region C during encoder
static constexpr size_t SZ_H2F    = (size_t)Tt * Bb * Hh * 4;        // 16,777,216
static constexpr size_t OFF_H     = OFF_H2F + SZ_H2F;
static constexpr size_t OFF_GXD   = OFF_H + (size_t)Bb * Hh * 4;
static constexpr size_t OFF_HENC  = OFF_GXD + 12288;
static constexpr size_t OFF_ZB    = OFF_HENC + (size_t)Bb * Zz * 4;
static constexpr size_t OFF_BV    = OFF_ZB + (size_t)Bb * Zz * 4;
static constexpr size_t OFF_BI    = OFF_BV + 16384;
static constexpr size_t OFF_BAR   = OFF_BI + 16384;
// BAR: FLG[256] at u32 idx bid*16 (64B lines). 4096 u32.

static constexpr size_t SZ_HAB    = (size_t)Bb * 2 * Hh * 2;         // 262,144 per step-buffer

// ---------------- small helpers ----------------
DI u16 f2bf(float f) {                       // f32 -> bf16 RNE
  u32 u = __float_as_uint(f);
  u32 r = (u + 0x7FFFu + ((u >> 16) & 1u)) >> 16;
  return (u16)r;
}
DI float bf2f(u16 h) { return __uint_as_float(((u32)h) << 16); }

DI f32x4 mfma16(short8 a, short8 b, f32x4 c) {
  return __builtin_amdgcn_mfma_f32_16x16x32_bf16(a, b, c, 0, 0, 0);
}
DI void llds16(const u16* g, u16* l) {       // async global->LDS, 16B/lane
  __builtin_amdgcn_global_load_lds(
      (const __attribute__((address_space(1))) u32*)g,
      (__attribute__((address_space(3))) u32*)l, 16, 0, 0);
}

// agent-scope ops: write-through past L2 to L3 coherence point / L2-bypassing load.
DI void ag_store_u32(u32* p, u32 v) {
  __hip_atomic_store(p, v, __ATOMIC_RELAXED, __HIP_MEMORY_SCOPE_AGENT);
}
DI u32 ag_load_u32(const u32* p) {
  return __hip_atomic_load((u32*)p, __ATOMIC_RELAXED, __HIP_MEMORY_SCOPE_AGENT);
}
DI void ag_store_f32(float* p, float v) {
  __hip_atomic_store(p, v, __ATOMIC_RELAXED, __HIP_MEMORY_SCOPE_AGENT);
}

// per-step hA buffer: regions A (XS, 192) | B (WIHE3, 36) | C (H2F, 29). Written once
// (sc stores, step st-1), read once (plain b128, step st) -> no stale L2 copies possible.
DI u16* hbuf_dev(char* rA, char* rB, char* rC, int i) {
  if (i < 192) return (u16*)(rA + (size_t)i * SZ_HAB);
  if (i < 228) return (u16*)(rB + (size_t)(i - 192) * SZ_HAB);
  return (u16*)(rC + (size_t)(i - 228) * SZ_HAB);
}

// ---------------- utility kernels ----------------
__global__ void k_zero(u32* p, int n) {
  for (int i = blockIdx.x * 256 + threadIdx.x; i < n; i += gridDim.x * 256) p[i] = 0;
}

__global__ void k_tobf(const float* __restrict__ W, u16* __restrict__ Wb, int n) {
  for (int i = blockIdx.x * 256 + threadIdx.x; i < n; i += gridDim.x * 256) Wb[i] = f2bf(W[i]);
}

// x = emb_enc[token] gathered as plain bf16 (S*B x E)
__global__ void k_xgather(const int* __restrict__ inp, const float* __restrict__ emb,
                          u16* __restrict__ xs) {
  int n = Ss * Bb * Ee;
  for (int i = blockIdx.x * 256 + threadIdx.x; i < n; i += gridDim.x * 256) {
    int m = i >> 9, k = i & (Ee - 1);
    xs[i] = f2bf(emb[(size_t)inp[m] * Ee + k]);
  }
}

// gxd[g] = emb_dec[EOS] . Wih_d[g] + bih_d[g]   (exact f32, once)
__global__ void k_gxd(const float* __restrict__ emb_dec, const float* __restrict__ Wih_d,
                      const float* __restrict__ bih_d, float* __restrict__ gxd) {
  int g = blockIdx.x * 256 + threadIdx.x;
  if (g >= G3) return;
  const float* er = emb_dec + 2 * Ee;        // EOS_ID = 2
  const float* wr = Wih_d + (size_t)g * Ee;
  float s = 0.f;
  for (int e = 0; e < Ee; e++) s += er[e] * wr[e];
  gxd[g] = s + bih_d[g];
}

// ---------------- generic GEMM: C[m][n] = sum_k A[m][k]*B[n][k] + bias[n] ----------------
__global__ __launch_bounds__(256, 2) void gemm_bt(
    const u16* __restrict__ A, const u16* __restrict__ Bw, const float* __restrict__ bias,
    float* __restrict__ C, int M, int N, int K) {
  __shared__ __align__(16) u16 As[128 * 32];
  __shared__ __align__(16) u16 Bs[128 * 32];
  int tid = threadIdx.x;
  int wave = tid >> 6, lane = tid & 63;
  int wr = wave >> 1, wc = wave & 1;
  int m0 = blockIdx.y * 128, n0 = blockIdx.x * 128;
  f32x4 acc[4][4];
#pragma unroll
  for (int i = 0; i < 4; i++)
#pragma unroll
    for (int j = 0; j < 4; j++) acc[i][j] = (f32x4){0.f, 0.f, 0.f, 0.f};

  int lrow = lane >> 2, lcol = (lane & 3) * 8;
  int r15 = lane & 15, kk = (lane >> 4) * 8;

  for (int k0 = 0; k0 < K; k0 += 32) {
    __syncthreads();
#pragma unroll
    for (int rch = 0; rch < 2; rch++) {
      int c = rch * 4 + wave;
      int row = c * 16 + lrow;
      llds16(A  + (size_t)(m0 + row) * K + k0 + lcol, &As[c * 512]);
      llds16(Bw + (size_t)(n0 + row) * K + k0 + lcol, &Bs[c * 512]);
    }
    __syncthreads();
    short8 af[4], bfv[4];
#pragma unroll
    for (int mi = 0; mi < 4; mi++)
      af[mi] = *(const short8*)&As[(wr * 64 + mi * 16 + r15) * 32 + kk];
#pragma unroll
    for (int ni = 0; ni < 4; ni++)
      bfv[ni] = *(const short8*)&Bs[(wc * 64 + ni * 16 + r15) * 32 + kk];
#pragma unroll
    for (int mi = 0; mi < 4; mi++)
#pragma unroll
      for (int ni = 0; ni < 4; ni++) acc[mi][ni] = mfma16(af[mi], bfv[ni], acc[mi][ni]);
  }
#pragma unroll
  for (int mi = 0; mi < 4; mi++)
#pragma unroll
    for (int ni = 0; ni < 4; ni++) {
      int col = n0 + wc * 64 + ni * 16 + r15;
      float bs = bias[col];
#pragma unroll
      for (int i = 0; i < 4; i++) {
        int row = m0 + wr * 64 + mi * 16 + (lane >> 4) * 4 + i;
        C[(size_t)row * N + col] = acc[mi][ni][i] + bs;
      }
    }
}

// Grouped 1D-grid variant for the vocab GEMM (B slice L2-resident per XCD).
__global__ __launch_bounds__(256, 2) void gemm_grp(
    const u16* __restrict__ A, const u16* __restrict__ Bw, const float* __restrict__ bias,
    float* __restrict__ C, int M, int N, int K, int GN) {
  __shared__ __align__(16) u16 As[128 * 32];
  __shared__ __align__(16) u16 Bs[128 * 32];
  int tid = threadIdx.x;
  int wave = tid >> 6, lane = tid & 63;
  int wr = wave >> 1, wc = wave & 1;
  int mp = M >> 7;
  int perg = mp * GN;
  int grp = blockIdx.x / perg;
  int rem = blockIdx.x - grp * perg;
  int m0 = (rem / GN) * 128;
  int n0 = (grp * GN + rem % GN) * 128;
  f32x4 acc[4][4];
#pragma unroll
  for (int i = 0; i < 4; i++)
#pragma unroll
    for (int j = 0; j < 4; j++) acc[i][j] = (f32x4){0.f, 0.f, 0.f, 0.f};

  int lrow = lane >> 2, lcol = (lane & 3) * 8;
  int r15 = lane & 15, kk = (lane >> 4) * 8;

  for (int k0 = 0; k0 < K; k0 += 32) {
    __syncthreads();
#pragma unroll
    for (int rch = 0; rch < 2; rch++) {
      int c = rch * 4 + wave;
      int row = c * 16 + lrow;
      llds16(A  + (size_t)(m0 + row) * K + k0 + lcol, &As[c * 512]);
      llds16(Bw + (size_t)(n0 + row) * K + k0 + lcol, &Bs[c * 512]);
    }
    __syncthreads();
    short8 af[4], bfv[4];
#pragma unroll
    for (int mi = 0; mi < 4; mi++)
      af[mi] = *(const short8*)&As[(wr * 64 + mi * 16 + r15) * 32 + kk];
#pragma unroll
    for (int ni = 0; ni < 4; ni++)
      bfv[ni] = *(const short8*)&Bs[(wc * 64 + ni * 16 + r15) * 32 + kk];
#pragma unroll
    for (int mi = 0; mi < 4; mi++)
#pragma unroll
      for (int ni = 0; ni < 4; ni++) acc[mi][ni] = mfma16(af[mi], bfv[ni], acc[mi][ni]);
  }
#pragma unroll
  for (int mi = 0; mi < 4; mi++)
#pragma unroll
    for (int ni = 0; ni < 4; ni++) {
      int col = n0 + wc * 64 + ni * 16 + r15;
      float bs = bias[col];
#pragma unroll
      for (int i = 0; i < 4; i++) {
        int row = m0 + wr * 64 + mi * 16 + (lane >> 4) * 4 + i;
        C[(size_t)row * N + col] = acc[mi][ni][i] + bs;
      }
    }
}

// ---------------- persistent GRU phase (v6 REVERT: wave0-only flag polling) ----------------
// grid 256 = 64 jt x 4 bq; block 512 = 8 waves splitting K=1024 into 8x128.
// Barrier spans only a bq-domain (64 blocks): each block sc-stores FLG[bid]=st+1 on its
// own 64B line; ONLY wave0 of each block polls the 64 domain flags (one 64-lane load
// per iteration), then post-poll syncthreads releases the other waves. Proven 1175us.
// (R12's per-wave producer-polling removed: +16% regression + latent sC race.)
template <int DEC>
__global__ __launch_bounds__(512, 1) void k_pers(
    const u16* __restrict__ W, const float* __restrict__ bhh, const float* __restrict__ gx0,
    char* rA, char* rB, char* rC, float* Hst, float* h2f0, u16* h2b0, u32* bar) {
  int tid = threadIdx.x, wave = tid >> 6, lane = tid & 63;
  int r15 = lane & 15, kk = (lane >> 4) * 8;
  int bq = blockIdx.x & 3, jt = blockIdx.x >> 2;
  int b0 = bq * 16, j0 = jt * 16;
  int kbase = wave * 128;
  const int NSTEP = DEC ? Tt : Ss;

  __shared__ float sC[8][64][13];              // stride 13 -> conflict-free
  __shared__ float hT[256];                    // h tile [bl*16+jc]
  __shared__ __align__(8) u16 stg[2][16][16];  // hi/lo staging

  int bl = tid >> 4, jc = tid & 15;            // epilogue mapping (tid<256)
  float br = 0.f, bz = 0.f, bn = 0.f;
  float xr = 0.f, xz = 0.f, xn = 0.f;
  if (tid < 256) {
    hT[tid] = DEC ? Hst[(size_t)(b0 + bl) * Hh + j0 + jc] : 0.f;
    int j = j0 + jc;
    br = bhh[j]; bz = bhh[Hh + j]; bn = bhh[2 * Hh + j];
    if (DEC) { xr = gx0[j]; xz = gx0[Hh + j]; xn = gx0[2 * Hh + j]; }
    else {                                     // prologue gx load, step 0
      const float* gr = gx0 + (size_t)(b0 + bl) * G3;
      xr = gr[j]; xz = gr[Hh + j]; xn = gr[2 * Hh + j];
    }
  }
  __syncthreads();

  const u16* Wrow = W + (size_t)(j0 + r15) * Hh + kbase + kk;
  int lsrc = (bl >> 2) * 16 + jc;              // partials source for (bl,jc)
  int isrc = bl & 3;
  int flgidx = (lane * 4 + bq) * 16;           // poll address per lane (lane = jt')

  for (int st = 0; st < NSTEP; st++) {
    const u16* hin = hbuf_dev(rA, rB, rC, st);

    f32x4 acc[3];
#pragma unroll
    for (int g = 0; g < 3; g++) acc[g] = (f32x4){0.f, 0.f, 0.f, 0.f};
    const u16* Ab = hin + (size_t)(b0 + r15) * 2048 + kbase + kk;
#pragma unroll
    for (int ks = 0; ks < 4; ks++) {
      int ko = ks * 32;
      short8 ah = *(const short8*)(Ab + ko);          // h_hi (plain b128)
      short8 al = *(const short8*)(Ab + 1024 + ko);   // h_lo
      short8 w0 = *(const short8*)(Wrow + ko);
      short8 w1 = *(const short8*)(Wrow + (size_t)Hh * Hh + ko);
      short8 w2 = *(const short8*)(Wrow + (size_t)2 * Hh * Hh + ko);
      acc[0] = mfma16(ah, w0, acc[0]);
      acc[1] = mfma16(ah, w1, acc[1]);
      acc[2] = mfma16(ah, w2, acc[2]);
      acc[0] = mfma16(al, w0, acc[0]);
      acc[1] = mfma16(al, w1, acc[1]);
      acc[2] = mfma16(al, w2, acc[2]);
    }
#pragma unroll
    for (int g = 0; g < 3; g++)
#pragma unroll
      for (int i = 0; i < 4; i++) sC[wave][lane][g * 4 + i] = acc[g][i];
    __syncthreads();

    if (tid < 256) {
      float hgr = br, hgz = bz, hgn = bn;
#pragma unroll
      for (int w = 0; w < 8; w++) {              // fixed order -> deterministic
        hgr += sC[w][lsrc][isrc];
        hgz += sC[w][lsrc][4 + isrc];
        hgn += sC[w][lsrc][8 + isrc];
      }
      float rg = 1.0f / (1.0f + expf(-(xr + hgr)));
      float zg = 1.0f / (1.0f + expf(-(xz + hgz)));
      float ng = tanhf(xn + rg * hgn);
      float hn = (1.0f - zg) * ng + zg * hT[tid];
      hT[tid] = hn;
      u16 hi = f2bf(hn), lo = f2bf(hn - bf2f(hi));
      stg[0][bl][jc] = hi;
      stg[1][bl][jc] = lo;
      if (DEC) ag_store_f32(&h2f0[((size_t)st * Bb + b0 + bl) * Hh + j0 + jc], hn);
    }
    __syncthreads();

    // distributed sc stores of the next-step buffer (skipped on last step)
    if (tid < 256) {
      int part = tid >> 7, idx = tid & 127, row = idx >> 3, dw = idx & 7;
      if (st + 1 < NSTEP) {
        u16* hout = hbuf_dev(rA, rB, rC, st + 1);
        u32 val = ((const u32*)&stg[part][row][0])[dw];
        ag_store_u32((u32*)(hout + (size_t)(b0 + row) * 2048 + part * 1024 + j0) + dw, val);
      }
      if (DEC && tid < 128) {
        u16* h2b = h2b0 + (size_t)st * Bb * Hh;
        ag_store_u32((u32*)(h2b + (size_t)(b0 + row) * Hh + j0) + dw,
                     ((const u32*)&stg[0][row][0])[dw]);
      }
    }

    if (st + 1 < NSTEP) {
      asm volatile("s_waitcnt vmcnt(0)" ::: "memory");   // own sc stores at L3
      __syncthreads();                                    // whole block drained
      if (tid == 0)
        ag_store_u32(&bar[blockIdx.x * 16], (u32)(st + 1));  // flag: own 64B line
      // prefetch gx(st+1) under the barrier wait (encoder only)
      if (!DEC && tid < 256) {
        const float* gr = gx0 + ((size_t)(st + 1) * Bb + b0 + bl) * G3;
        int j = j0 + jc;
        xr = gr[j]; xz = gr[Hh + j]; xn = gr[2 * Hh + j];
      }
      if (wave == 0) {                         // only wave0 polls (256 pollers total)
        for (;;) {
          int v = (int)ag_load_u32(&bar[flgidx]);
          if (__all(v >= st + 1)) break;
          __builtin_amdgcn_s_sleep(1);
        }
      }
      __syncthreads();                         // release other waves
    }
  }

  if (!DEC && tid < 256)
    Hst[(size_t)(b0 + bl) * Hh + j0 + jc] = hT[tid];
}

// ---------------- fallback per-step kernel (if coop launch fails) ----------------
template <int DEC>
__global__ __launch_bounds__(512, 1) void k_step3(
    const u16* __restrict__ W, const float* __restrict__ bhh, const float* __restrict__ gxp,
    const u16* __restrict__ hAin, u16* __restrict__ hAout, float* __restrict__ h,
    float* __restrict__ h2f, u16* __restrict__ h2b) {
  __shared__ float sC[4][64][13];
  int tid = threadIdx.x, wave = tid >> 6, lane = tid & 63;
  int mw = wave & 3, khalf = wave >> 2;
  int m0 = mw * 16;
  int r15 = lane & 15, kk = (lane >> 4) * 8;
  int j0 = blockIdx.x * 16;
  int kbase = khalf * 512;

  f32x4 acc[3];
#pragma unroll
  for (int g = 0; g < 3; g++) acc[g] = (f32x4){0.f, 0.f, 0.f, 0.f};

  const u16* Ah = hAin + (size_t)(m0 + r15) * 2048 + kbase + kk;
  const u16* Wr = W + (size_t)(j0 + r15) * Hh + kbase + kk;
#pragma unroll 4
  for (int ks = 0; ks < 16; ks++) {
    int ko = ks * 32;
    short8 ah = *(const short8*)(Ah + ko);
    short8 al = *(const short8*)(Ah + 1024 + ko);
    short8 b0 = *(const short8*)(Wr + ko);
    short8 b1 = *(const short8*)(Wr + (size_t)Hh * Hh + ko);
    short8 b2 = *(const short8*)(Wr + (size_t)2 * Hh * Hh + ko);
    acc[0] = mfma16(ah, b0, acc[0]);
    acc[1] = mfma16(ah, b1, acc[1]);
    acc[2] = mfma16(ah, b2, acc[2]);
    acc[0] = mfma16(al, b0, acc[0]);
    acc[1] = mfma16(al, b1, acc[1]);
    acc[2] = mfma16(al, b2, acc[2]);
  }

  if (khalf == 1) {
#pragma unroll
    for (int g = 0; g < 3; g++)
#pragma unroll
      for (int i = 0; i < 4; i++) sC[mw][lane][g * 4 + i] = acc[g][i];
  }
  __syncthreads();
  if (khalf == 1) return;

  int j = j0 + r15;
  float br = bhh[j], bz = bhh[Hh + j], bn = bhh[2 * Hh + j];
  float xrD = 0.f, xzD = 0.f, xnD = 0.f;
  if (DEC) { xrD = gxp[j]; xzD = gxp[Hh + j]; xnD = gxp[2 * Hh + j]; }
#pragma unroll
  for (int i = 0; i < 4; i++) {
    int b = m0 + (lane >> 4) * 4 + i;
    float hgr = acc[0][i] + sC[mw][lane][i]     + br;
    float hgz = acc[1][i] + sC[mw][lane][4 + i] + bz;
    float hgn = acc[2][i] + sC[mw][lane][8 + i] + bn;
    float xr, xz, xn;
    if (DEC) { xr = xrD; xz = xzD; xn = xnD; }
    else {
      const float* gr = gxp + (size_t)b * G3;
      xr = gr[j]; xz = gr[Hh + j]; xn = gr[2 * Hh + j];
    }
    float rg = 1.0f / (1.0f + expf(-(xr + hgr)));
    float zg = 1.0f / (1.0f + expf(-(xz + hgz)));
    float ng = tanhf(xn + rg * hgn);
    float hold = h[(size_t)b * Hh + j];
    float hn = (1.0f - zg) * ng + zg * hold;
    h[(size_t)b * Hh + j] = hn;
    u16 hi = f2bf(hn);
    u16 lo = f2bf(hn - bf2f(hi));
    hAout[(size_t)b * 2048 + j] = hi;
    hAout[(size_t)b * 2048 + 1024 + j] = lo;
    if (DEC) {
      h2f[(size_t)b * Hh + j] = hn;
      h2b[(size_t)b * Hh + j] = hi;
    }
  }
}

// ---------------- heads (exact f32) ----------------
__global__ __launch_bounds__(256, 2) void k_head1(const float* __restrict__ h,
    const float* __restrict__ Wenc, const float* __restrict__ benc, float* __restrict__ henc) {
  int b = blockIdx.x;
  __shared__ float hs[Hh];
  for (int k = threadIdx.x; k < Hh; k += 256) hs[k] = h[(size_t)b * Hh + k];
  __syncthreads();
  int q = threadIdx.x;
  const float* wrw = Wenc + (size_t)q * Hh;
  float s = 0.f;
  for (int k = 0; k < Hh; k++) s += hs[k] * wrw[k];
  henc[b * Zz + q] = s + benc[q];
}

__global__ __launch_bounds__(256, 2) void k_head2(const float* __restrict__ henc,
    const float* __restrict__ Wloc, const float* __restrict__ bloc,
    const float* __restrict__ Wsc, const float* __restrict__ bsc,
    const float* __restrict__ eps, float* __restrict__ outLoc, float* __restrict__ outSc,
    float* __restrict__ zb) {
  int b = blockIdx.x;
  __shared__ float hs[Zz];
  if (threadIdx.x < Zz) hs[threadIdx.x] = henc[b * Zz + threadIdx.x];
  __syncthreads();
  int q = threadIdx.x;
  const float* wl = Wloc + (size_t)q * Zz;
  const float* wsp = Wsc + (size_t)q * Zz;
  float sl = 0.f, ssum = 0.f;
  for (int k = 0; k < Zz; k++) { sl += hs[k] * wl[k]; ssum += hs[k] * wsp[k]; }
  sl += bloc[q]; ssum += bsc[q];
  float sp = fmaxf(ssum, 0.f) + log1pf(expf(-fabsf(ssum)));  // softplus, stable
  float zv = sl + eps[b * Zz + q] * expf(0.5f * sp);
  outLoc[b * Zz + q] = sl;
  outSc[b * Zz + q] = sp;
  zb[b * Zz + q] = zv;
}

__global__ __launch_bounds__(256, 2) void k_head3(const float* __restrict__ zb,
    const float* __restrict__ Wdec, const float* __restrict__ bdec,
    float* __restrict__ h, u16* __restrict__ hA0) {
  int b = blockIdx.x;
  __shared__ float zs[Zz];
  if (threadIdx.x < Zz) zs[threadIdx.x] = zb[b * Zz + threadIdx.x];
  __syncthreads();
  for (int j = threadIdx.x; j < Hh; j += 256) {
    const float* wrw = Wdec + (size_t)j * Zz;
    float s = 0.f;
    for (int k = 0; k < Zz; k++) s += zs[k] * wrw[k];
    s += bdec[j];
    h[(size_t)b * Hh + j] = s;
    u16 hi = f2bf(s);
    u16 lo = f2bf(s - bf2f(hi));
    hA0[(size_t)b * 2048 + j] = hi;
    hA0[(size_t)b * 2048 + 1024 + j] = lo;
  }
}

// ---------------- fused softmax v3: row held in registers, 1 read + 1 write ----------------
__global__ __launch_bounds__(1024, 4) void k_soft(
    float* __restrict__ logits, const float* __restrict__ h2f,
    const float* __restrict__ Wvoc, const float* __restrict__ bvoc,
    float* __restrict__ bestv, int* __restrict__ besti) {
  __shared__ float hrow[Hh];
  __shared__ float red[16];
  __shared__ float srm, ssum, slse;
  __shared__ int lcnt, scc;
  __shared__ int lcand[32];
  __shared__ float lex[32], del[32];
  int r = blockIdx.x;
  int tid = threadIdx.x, wave = tid >> 6, lane = tid & 63;
  float* grow = logits + (size_t)r * Vv;
  if (tid == 0) lcnt = 0;
  hrow[tid] = h2f[(size_t)r * Hh + tid];
  f32x4 vals[8];
  float m = -3.0e38f;
#pragma unroll
  for (int it = 0; it < 8; it++) {
    int c = tid * 4 + it * 4096;
    if (c < Vv) {
      vals[it] = *(const f32x4*)(grow + c);
      m = fmaxf(fmaxf(m, vals[it].x), fmaxf(vals[it].y, fmaxf(vals[it].z, vals[it].w)));
    }
  }
  for (int o = 32; o; o >>= 1) m = fmaxf(m, __shfl_xor(m, o));
  if (lane == 0) red[wave] = m;
  __syncthreads();
  if (tid == 0) {
    float t = red[0];
    for (int i = 1; i < 16; i++) t = fmaxf(t, red[i]);
    srm = t;
  }
  __syncthreads();
  float rm = srm;
  float s = 0.f;
#pragma unroll
  for (int it = 0; it < 8; it++) {
    int c = tid * 4 + it * 4096;
    if (c < Vv) {
      f32x4 v = vals[it];
      s += expf(v.x - rm) + expf(v.y - rm) + expf(v.z - rm) + expf(v.w - rm);
      if (v.x >= rm - 0.0625f) { int sl = atomicAdd(&lcnt, 1); if (sl < 32) lcand[sl] = c; }
      if (v.y >= rm - 0.0625f) { int sl = atomicAdd(&lcnt, 1); if (sl < 32) lcand[sl] = c + 1; }
      if (v.z >= rm - 0.0625f) { int sl = atomicAdd(&lcnt, 1); if (sl < 32) lcand[sl] = c + 2; }
      if (v.w >= rm - 0.0625f) { int sl = atomicAdd(&lcnt, 1); if (sl < 32) lcand[sl] = c + 3; }
    }
  }
  for (int o = 32; o; o >>= 1) s += __shfl_xor(s, o);
  if (lane == 0) red[wave] = s;
  __syncthreads();
  if (tid == 0) {
    float t = 0.f;
    for (int i = 0; i < 16; i++) t += red[i];       // fixed order -> deterministic
    ssum = t;
    int cc = lcnt < 32 ? lcnt : 32;
    for (int i = 0; i < cc; i++)                    // sort ascending -> determinism
      for (int k2 = i + 1; k2 < cc; k2++)
        if (lcand[k2] < lcand[i]) { int q = lcand[i]; lcand[i] = lcand[k2]; lcand[k2] = q; }
    scc = cc;
  }
  __syncthreads();
  int cnt = scc;
  for (int ci = wave; ci < cnt; ci += 16) {         // exact-f32 candidate recompute
    int v = lcand[ci];
    const float* wrw = Wvoc + (size_t)v * Hh;
    float sd = 0.f;
    for (int k = lane; k < Hh; k += 64) sd += hrow[k] * wrw[k];
    for (int o = 32; o; o >>= 1) sd += __shfl_xor(sd, o);
    if (lane == 0) {
      float le = sd + bvoc[v];
      lex[ci] = le;
      del[ci] = expf(le - rm) - expf(grow[v] - rm);
    }
  }
  __syncthreads();
  if (tid == 0) {
    float se = ssum;
    for (int i = 0; i < cnt; i++) se += del[i];
    float lse = rm + logf(se);
    slse = lse;
    float bv = -3.0e38f; int bvi = 0;
    for (int i = 0; i < cnt; i++)
      if (lex[i] > bv) { bv = lex[i]; bvi = lcand[i]; }  // sorted -> ties keep lowest v
    bestv[r] = bv - lse;
    besti[r] = (r & 63) * Vv + bvi;                  // flat index b*V + v
  }
  __syncthreads();
  float l = slse;
#pragma unroll
  for (int it = 0; it < 8; it++) {
    int c = tid * 4 + it * 4096;
    if (c < Vv) {
      f32x4 v = vals[it];
      v.x -= l; v.y -= l; v.z -= l; v.w -= l;
      *(f32x4*)(grow + c) = v;
    }
  }
}

// ---------------- per-step global argmax -> seq ----------------
__global__ void k_argmax(const float* __restrict__ bestv, const int* __restrict__ besti,
                         float* __restrict__ outseq) {
  int tid = threadIdx.x;
  if (tid == 0) outseq[0] = 1.0f;
  for (int t = 0; t < Tt; t++) {
    float v = bestv[t * 64 + tid];
    int ii = besti[t * 64 + tid];
    for (int o = 1; o < 64; o <<= 1) {
      float ov = __shfl_xor(v, o);
      int oi = __shfl_xor(ii, o);
      if (ov > v || (ov == v && oi < ii)) { v = ov; ii = oi; }
    }
    if (tid == 0) outseq[1 + t] = (float)ii;
  }
}

// ---------------- host: launch sequence ----------------
extern "C" void kernel_launch(void* const* d_in, const int* in_sizes, int n_in,
                              void* d_out, int out_size, void* d_ws, size_t ws_size,
                              hipStream_t stream) {
  (void)in_sizes; (void)n_in; (void)out_size; (void)ws_size;
  const int*   inp     = (const int*)d_in[0];
  const float* eps     = (const float*)d_in[1];
  const float* emb_enc = (const float*)d_in[2];
  const float* Wih_e   = (const float*)d_in[3];
  const float* Whh_e   = (const float*)d_in[4];
  const float* bih_e   = (const float*)d_in[5];
  const float* bhh_e   = (const float*)d_in[6];
  const float* W_enc   = (const float*)d_in[7];
  const float* b_enc   = (const float*)d_in[8];
  const float* W_loc   = (const float*)d_in[9];
  const float* b_loc   = (const float*)d_in[10];
  const float* W_sc    = (const float*)d_in[11];
  const float* b_sc    = (const float*)d_in[12];
  const float* emb_dec = (const float*)d_in[13];
  const float* W_dec   = (const float*)d_in[14];
  const float* b_dec   = (const float*)d_in[15];
  const float* Wih_d   = (const float*)d_in[16];
  const float* Whh_d   = (const float*)d_in[17];
  const float* bih_d   = (const float*)d_in[18];
  const float* bhh_d   = (const float*)d_in[19];
  const float* W_voc   = (const float*)d_in[20];
  const float* b_voc   = (const float*)d_in[21];

  char* ws = (char*)d_ws;
  u16*   WHHE  = (u16*)(ws + OFF_WHHE);
  u16*   WHHD  = (u16*)(ws + OFF_WHHD);
  u16*   WIHB  = (u16*)(ws + OFF_WIHE3);      // plain bf16 Wih_e [3072][512]
  u16*   WVOC  = (u16*)(ws + OFF_WVOC);
  u16*   XS    = (u16*)(ws + OFF_XS);         // plain bf16 x [16384][512]
  float* GX    = (float*)(ws + OFF_GX);
  float* Hst   = (float*)(ws + OFF_H);
  float* H2F   = (float*)(ws + OFF_H2F);
  u16*   H2B   = (u16*)(ws + OFF_H2B);
  float* GXD   = (float*)(ws + OFF_GXD);
  float* HENC  = (float*)(ws + OFF_HENC);
  float* ZB    = (float*)(ws + OFF_ZB);
  float* BV    = (float*)(ws + OFF_BV);
  int*   BI    = (int*)(ws + OFF_BI);
  u32*   BAR   = (u32*)(ws + OFF_BAR);

  char* rA = ws + OFF_XS;      // step-buffer regions
  char* rB = ws + OFF_WIHE3;
  char* rC = ws + OFF_H2F;
  auto hbuf = [&](int i) -> u16* {
    if (i < 192) return (u16*)(rA + (size_t)i * SZ_HAB);
    if (i < 228) return (u16*)(rB + (size_t)(i - 192) * SZ_HAB);
    return (u16*)(rC + (size_t)(i - 228) * SZ_HAB);
  };

  float* out     = (float*)d_out;
  float* logits  = out;                                   // (T*B, V) f32
  float* outseq  = out + (size_t)Tt * Bb * Vv;
  float* outloc  = outseq + (Tt + 1);
  float* outsc   = outloc + Bb * Zz;

  // --- weight conversions ---
  k_tobf<<<1024, 256, 0, stream>>>(Whh_e, WHHE, G3 * Hh);
  k_tobf<<<1024, 256, 0, stream>>>(Whh_d, WHHD, G3 * Hh);
  k_tobf<<<512, 256, 0, stream>>>(Wih_e, WIHB, G3 * Ee);
  k_tobf<<<2048, 256, 0, stream>>>(W_voc, WVOC, Vv * Hh);
  k_xgather<<<2048, 256, 0, stream>>>(inp, emb_enc, XS);

  // --- gx = x * Wih_e^T + bih_e   (M=16384, N=3072, K=512, plain bf16) ---
  {
    dim3 g(G3 / 128, (Ss * Bb) / 128);
    gemm_bt<<<g, 256, 0, stream>>>(XS, WIHB, bih_e, GX, Ss * Bb, G3, Ee);
  }
  k_gxd<<<12, 256, 0, stream>>>(emb_dec, Wih_d, bih_d, GXD);
  k_zero<<<64, 256, 0, stream>>>((u32*)hbuf(0), (int)(SZ_HAB / 4));  // h0 = 0
  k_zero<<<1, 256, 0, stream>>>(BAR, 4096);

  // --- encoder: persistent cooperative (256 steps), fallback = per-step loop ---
  hipError_t ce;
  {
    const u16* a0 = WHHE; const float* a1 = bhh_e; const float* a2 = GX;
    char* a3 = rA; char* a4 = rB; char* a5 = rC; float* a6 = Hst;
    float* a7 = nullptr; u16* a8 = nullptr; u32* a9 = BAR;
    void* args[] = {&a0,&a1,&a2,&a3,&a4,&a5,&a6,&a7,&a8,&a9};
    ce = hipLaunchCooperativeKernel(reinterpret_cast<void*>(&k_pers<0>),
                                    dim3(256), dim3(512), args, 0, stream);
  }
  if (ce != hipSuccess) {
    for (int s = 0; s < Ss; s++)
      k_step3<0><<<64, 512, 0, stream>>>(WHHE, bhh_e, GX + (size_t)s * Bb * G3,
                                         hbuf(s), hbuf(s + 1), Hst, nullptr, nullptr);
  }

  // --- heads ---
  k_head1<<<64, 256, 0, stream>>>(Hst, W_enc, b_enc, HENC);
  k_head2<<<64, 256, 0, stream>>>(HENC, W_loc, b_loc, W_sc, b_sc, eps, outloc, outsc, ZB);
  k_head3<<<64, 256, 0, stream>>>(ZB, W_dec, b_dec, Hst, hbuf(0));
  k_zero<<<1, 256, 0, stream>>>(BAR, 4096);

  // --- decoder: persistent cooperative (64 steps), fallback = per-step loop ---
  {
    const u16* a0 = WHHD; const float* a1 = bhh_d; const float* a2 = GXD;
    char* a3 = rA; char* a4 = rB; char* a5 = rC; float* a6 = Hst;
    float* a7 = H2F; u16* a8 = H2B; u32* a9 = BAR;
    void* args[] = {&a0,&a1,&a2,&a3,&a4,&a5,&a6,&a7,&a8,&a9};
    hipError_t cd = hipLaunchCooperativeKernel(reinterpret_cast<void*>(&k_pers<1>),
                                               dim3(256), dim3(512), args, 0, stream);
    if (cd != hipSuccess) {
      for (int t = 0; t < Tt; t++)
        k_step3<1><<<64, 512, 0, stream>>>(WHHD, bhh_d, GXD, hbuf(t), hbuf(t + 1), Hst,
                                           H2F + (size_t)t * Bb * Hh,
                                           H2B + (size_t)t * Bb * Hh);
    }
  }

  // --- vocab projection: logits = h2 * Wvoc^T + b_voc  (M=4096, N=32000, K=1024) ---
  gemm_grp<<<8000, 256, 0, stream>>>(H2B, WVOC, b_voc, logits, Tt * Bb, Vv, Hh, 5);

  // --- fused softmax (stats + exact argmax refine + in-place log-softmax) ---
  k_soft<<<Tt * Bb, 1024, 0, stream>>>(logits, H2F, W_voc, b_voc, BV, BI);
  k_argmax<<<1, 64, 0, stream>>>(BV, BI, outseq);
}